// Round 2
// baseline (754.858 us; speedup 1.0000x reference)
//
#include <hip/hip_runtime.h>
#include <hip/hip_bf16.h>

#define N_NODES 100000
#define N_EDGES 1600000
#define D 128
#define NF (N_NODES * D)   // floats per feature matrix

// ---------------------------------------------------------------------------
// Kernel 1: in-degree count (int atomics, random addresses)
// ---------------------------------------------------------------------------
__global__ void deg_count_kernel(const int* __restrict__ dst,
                                 int* __restrict__ deg, int nE) {
    int e = blockIdx.x * blockDim.x + threadIdx.x;
    if (e < nE) atomicAdd(&deg[dst[e]], 1);
}

// ---------------------------------------------------------------------------
// Hierarchical exclusive scan: deg[100000] -> rowptr
//   scan1: per-block (1024) exclusive scan + block sums
//   scan2: exclusive scan of the <=128 block sums (single block)
//   scan3: add block offset, write rowptr and cursor, set rowptr[n]=nE
// ---------------------------------------------------------------------------
__global__ __launch_bounds__(1024) void scan1_kernel(
    const int* __restrict__ deg, int* __restrict__ rowptr,
    int* __restrict__ bsums, int n) {
    __shared__ int buf[1024];
    int i = blockIdx.x * 1024 + threadIdx.x;
    int v = (i < n) ? deg[i] : 0;
    buf[threadIdx.x] = v;
    __syncthreads();
    for (int off = 1; off < 1024; off <<= 1) {
        int t = (threadIdx.x >= off) ? buf[threadIdx.x - off] : 0;
        __syncthreads();
        if (threadIdx.x >= off) buf[threadIdx.x] += t;
        __syncthreads();
    }
    if (i < n) rowptr[i] = buf[threadIdx.x] - v;   // block-local exclusive
    if (threadIdx.x == 1023) bsums[blockIdx.x] = buf[1023];
}

__global__ __launch_bounds__(128) void scan2_kernel(int* __restrict__ bsums,
                                                    int nb) {
    __shared__ int buf[128];
    int v = (threadIdx.x < nb) ? bsums[threadIdx.x] : 0;
    buf[threadIdx.x] = v;
    __syncthreads();
    for (int off = 1; off < 128; off <<= 1) {
        int t = (threadIdx.x >= off) ? buf[threadIdx.x - off] : 0;
        __syncthreads();
        if (threadIdx.x >= off) buf[threadIdx.x] += t;
        __syncthreads();
    }
    if (threadIdx.x < nb) bsums[threadIdx.x] = buf[threadIdx.x] - v;  // excl
}

__global__ __launch_bounds__(1024) void scan3_kernel(
    int* __restrict__ rowptr, const int* __restrict__ bsums,
    int* __restrict__ cursor, int n, int nE) {
    int i = blockIdx.x * 1024 + threadIdx.x;
    if (i < n) {
        int r = rowptr[i] + bsums[blockIdx.x];
        rowptr[i] = r;
        cursor[i] = r;
    }
    if (i == 0) rowptr[n] = nE;
}

// ---------------------------------------------------------------------------
// CSR fill (cursor fetch-add per edge)
// ---------------------------------------------------------------------------
__global__ void csr_fill_kernel(const int* __restrict__ src,
                                const int* __restrict__ dst,
                                int* __restrict__ cursor,
                                int* __restrict__ col, int nE) {
    int e = blockIdx.x * blockDim.x + threadIdx.x;
    if (e < nE) {
        int d = dst[e];
        int p = atomicAdd(&cursor[d], 1);
        col[p] = src[e];
    }
}

// ---------------------------------------------------------------------------
// Gather-side mean aggregation. One wave (64 lanes) per node; each lane owns
// 2 channels (float2, 8B/lane -> 512B coalesced row read). No float atomics.
// X (51.2 MB) is L3-resident. Unroll x4 for load-chain ILP.
// ---------------------------------------------------------------------------
__global__ __launch_bounds__(256) void aggregate_mean_kernel(
    const float* __restrict__ X,
    const int* __restrict__ rowptr,
    const int* __restrict__ col,
    float* __restrict__ mean) {
    int node = (int)((blockIdx.x * blockDim.x + threadIdx.x) >> 6);
    int lane = threadIdx.x & 63;
    if (node >= N_NODES) return;
    int beg = rowptr[node];
    int end = rowptr[node + 1];
    float a0x = 0.f, a0y = 0.f, a1x = 0.f, a1y = 0.f;
    int p = beg;
    for (; p + 3 < end; p += 4) {
        int s0 = col[p];
        int s1 = col[p + 1];
        int s2 = col[p + 2];
        int s3 = col[p + 3];
        float2 v0 = ((const float2*)(X + (size_t)s0 * D))[lane];
        float2 v1 = ((const float2*)(X + (size_t)s1 * D))[lane];
        float2 v2 = ((const float2*)(X + (size_t)s2 * D))[lane];
        float2 v3 = ((const float2*)(X + (size_t)s3 * D))[lane];
        a0x += v0.x + v1.x;
        a0y += v0.y + v1.y;
        a1x += v2.x + v3.x;
        a1y += v2.y + v3.y;
    }
    for (; p < end; ++p) {
        int s = col[p];
        float2 v = ((const float2*)(X + (size_t)s * D))[lane];
        a0x += v.x;
        a0y += v.y;
    }
    int dg = end - beg;
    float invd = 1.0f / (float)(dg > 1 ? dg : 1);
    float2 o;
    o.x = (a0x + a1x) * invd;
    o.y = (a0y + a1y) * invd;
    ((float2*)(mean + (size_t)node * D))[lane] = o;
}

// ---------------------------------------------------------------------------
// Fused SAGE GEMM:  Out = relu(mean @ Wl + bias + Self @ Wr)
// [N,256] @ [256,128]: K-loop 0..255, first half (mean, Wl), second half
// (Self, Wr). Block tile 128x128, per-thread 8x8 as split column pair
// {4tx..4tx+3, 64+4tx..+3} (16B LDS lane stride -> all 32 banks, no
// conflict). Safe for Amean == Out (in-place): each block reads only its own
// output rows, all reads precede its stores.
// ---------------------------------------------------------------------------
#define BM 128
#define BK 32

__global__ __launch_bounds__(256) void sage_gemm_kernel(
    const float* __restrict__ Amean,   // [N,128]
    const float* __restrict__ Aself,   // [N,128]
    const float* __restrict__ Wl,      // [128,128] row-major (k, j)
    const float* __restrict__ Wr,      // [128,128]
    const float* __restrict__ bias,    // [128]
    float* __restrict__ Out,           // [N,128]
    int nrows) {
    __shared__ float As[BM][BK + 4];    // stride 36 floats
    __shared__ float Bs[BK][132];       // stride 132 floats

    const int tid = threadIdx.x;
    const int row0 = blockIdx.x * BM;
    const int tx = tid & 15;    // column pair {4tx.., 64+4tx..}
    const int ty = tid >> 4;    // rows 8*ty .. 8*ty+7

    float acc[8][8];   // [i][0..3] = cols 4tx..+3 ; [i][4..7] = 64+4tx..+3
#pragma unroll
    for (int i = 0; i < 8; i++)
#pragma unroll
        for (int j = 0; j < 8; j++) acc[i][j] = 0.f;

    for (int step = 0; step < 8; ++step) {
        const int k0 = step * BK;
        const float* A = (k0 < 128) ? Amean : Aself;
        const float* W = (k0 < 128) ? Wl : Wr;
        const int kc = k0 & 127;

        // stage A tile: each thread 16 consecutive floats (4x float4)
        {
            int r = tid >> 1;
            int kk0 = (tid & 1) * 16;
            int gr = row0 + r;
            if (gr >= nrows) gr = nrows - 1;
            const float4* srcp = (const float4*)(A + (size_t)gr * D + kc + kk0);
#pragma unroll
            for (int q = 0; q < 4; q++) {
                float4 v = srcp[q];
                *(float4*)&As[r][kk0 + 4 * q] = v;
            }
        }
        // stage B tile
        {
            int kk = tid >> 3;
            int c = tid & 7;
            const float4* srcp = (const float4*)(W + (size_t)(kc + kk) * D);
#pragma unroll
            for (int q = 0; q < 4; q++) {
                float4 v = srcp[c + 8 * q];
                *(float4*)&Bs[kk][(c + 8 * q) * 4] = v;
            }
        }
        __syncthreads();

#pragma unroll
        for (int kk = 0; kk < BK; ++kk) {
            float a[8], b[8];
#pragma unroll
            for (int i = 0; i < 8; i++) a[i] = As[ty * 8 + i][kk];
            float4 b0 = *(const float4*)&Bs[kk][tx * 4];
            float4 b1 = *(const float4*)&Bs[kk][64 + tx * 4];
            b[0] = b0.x; b[1] = b0.y; b[2] = b0.z; b[3] = b0.w;
            b[4] = b1.x; b[5] = b1.y; b[6] = b1.z; b[7] = b1.w;
#pragma unroll
            for (int i = 0; i < 8; i++)
#pragma unroll
                for (int j = 0; j < 8; j++) acc[i][j] += a[i] * b[j];
        }
        __syncthreads();
    }

    // epilogue: bias + relu + store (two float4 per row)
    float4 bv0 = *(const float4*)&bias[tx * 4];
    float4 bv1 = *(const float4*)&bias[64 + tx * 4];
#pragma unroll
    for (int i = 0; i < 8; i++) {
        int gr = row0 + ty * 8 + i;
        if (gr < nrows) {
            float4 o0, o1;
            o0.x = fmaxf(acc[i][0] + bv0.x, 0.f);
            o0.y = fmaxf(acc[i][1] + bv0.y, 0.f);
            o0.z = fmaxf(acc[i][2] + bv0.z, 0.f);
            o0.w = fmaxf(acc[i][3] + bv0.w, 0.f);
            o1.x = fmaxf(acc[i][4] + bv1.x, 0.f);
            o1.y = fmaxf(acc[i][5] + bv1.y, 0.f);
            o1.z = fmaxf(acc[i][6] + bv1.z, 0.f);
            o1.w = fmaxf(acc[i][7] + bv1.w, 0.f);
            *(float4*)(Out + (size_t)gr * D + tx * 4) = o0;
            *(float4*)(Out + (size_t)gr * D + 64 + tx * 4) = o1;
        }
    }
}

// ---------------------------------------------------------------------------
// Launch
// ---------------------------------------------------------------------------
extern "C" void kernel_launch(void* const* d_in, const int* in_sizes, int n_in,
                              void* d_out, int out_size, void* d_ws,
                              size_t ws_size, hipStream_t stream) {
    const float* x   = (const float*)d_in[0];
    const int*   ei  = (const int*)d_in[1];   // [2, E]: row0 = src, row1 = dst
    // d_in[2] edge_weight: unused by the reference
    const float* W0l = (const float*)d_in[3];
    const float* b0l = (const float*)d_in[4];
    const float* W0r = (const float*)d_in[5];
    const float* W2l = (const float*)d_in[6];
    const float* b2l = (const float*)d_in[7];
    const float* W2r = (const float*)d_in[8];

    const int* src = ei;
    const int* dst = ei + N_EDGES;

    float* fea = (float*)d_out;            // output 0: [N,128] (final)
    float* h   = (float*)d_out + NF;       // output 1 (mid feats): [N,128]
    // The fea slot doubles as the mean scratch buffer: layer-0 mean lives
    // there until layer-0 GEMM consumes it; layer-1 mean lives there and the
    // layer-1 GEMM overwrites it in place (block-exclusive rows => safe).
    float* meanbuf = fea;

    // workspace: ints only, ~7.6 MB
    char* ws = (char*)d_ws;
    int* deg    = (int*)ws;                    //   400,000 B
    int* rowptr = (int*)(ws + 400000);         //   400,004 B
    int* bsums  = (int*)(ws + 800032);         //       512 B
    int* cursor = (int*)(ws + 800544);         //   400,000 B
    int* col    = (int*)(ws + 1200544);        // 6,400,000 B

    const int nScanBlocks = (N_NODES + 1023) / 1024;   // 98

    // ---- build CSR (rebuilt every call; ws is re-poisoned) ----
    hipMemsetAsync(deg, 0, N_NODES * sizeof(int), stream);
    deg_count_kernel<<<(N_EDGES + 255) / 256, 256, 0, stream>>>(dst, deg, N_EDGES);
    scan1_kernel<<<nScanBlocks, 1024, 0, stream>>>(deg, rowptr, bsums, N_NODES);
    scan2_kernel<<<1, 128, 0, stream>>>(bsums, nScanBlocks);
    scan3_kernel<<<nScanBlocks, 1024, 0, stream>>>(rowptr, bsums, cursor,
                                                   N_NODES, N_EDGES);
    csr_fill_kernel<<<(N_EDGES + 255) / 256, 256, 0, stream>>>(src, dst, cursor,
                                                               col, N_EDGES);

    const int aggGrid = (N_NODES * 64 + 255) / 256;      // one wave per node
    const int gemmGrid = (N_NODES + BM - 1) / BM;

    // ---- layer 0: h = relu(mean(x) @ W0l + b0l + x @ W0r) ----
    aggregate_mean_kernel<<<aggGrid, 256, 0, stream>>>(x, rowptr, col, meanbuf);
    sage_gemm_kernel<<<gemmGrid, 256, 0, stream>>>(meanbuf, x, W0l, W0r, b0l, h,
                                                   N_NODES);

    // ---- layer 1: fea = relu(mean(h) @ W2l + b2l + h @ W2r), in place ----
    aggregate_mean_kernel<<<aggGrid, 256, 0, stream>>>(h, rowptr, col, meanbuf);
    sage_gemm_kernel<<<gemmGrid, 256, 0, stream>>>(meanbuf, h, W2l, W2r, b2l,
                                                   fea, N_NODES);
}

// Round 6
// 714.668 us; speedup vs baseline: 1.0562x; 1.0562x over previous
//
#include <hip/hip_runtime.h>
#include <hip/hip_bf16.h>

#define N_NODES 100000
#define N_EDGES 1600000
#define D 128
#define NF (N_NODES * D)   // floats per feature matrix

#define NGROUPS 8
#define NODES_PER_GROUP ((N_NODES + NGROUPS - 1) / NGROUPS)   // 12500
#define EPB 4096    // edges per chunk for partitioned passes

// ---------------------------------------------------------------------------
// Kernel 1: in-degree count, XCD-partitioned. Block b handles only dst range
// (b&7); with blockIdx%8 -> XCD round-robin each XCD's atomics target one
// 50 KB range -> line locality at the device-scope atomic unit. Correct under
// any block->XCD mapping (the group test is just a filter; every edge is
// counted exactly once by exactly one block).
// ---------------------------------------------------------------------------
__global__ __launch_bounds__(256) void deg_count_part_kernel(
    const int* __restrict__ dst, int* __restrict__ deg, int nE) {
    const int g = blockIdx.x & (NGROUPS - 1);
    const int chunk = blockIdx.x >> 3;
    const int base = chunk * EPB;
    const unsigned lo = (unsigned)(g * NODES_PER_GROUP);
    for (int i = threadIdx.x; i < EPB; i += 256) {
        int e = base + i;
        if (e >= nE) break;
        int d = dst[e];
        if ((unsigned)(d - lo) < (unsigned)NODES_PER_GROUP) {
            atomicAdd(&deg[d], 1);
        }
    }
}

// ---------------------------------------------------------------------------
// Hierarchical exclusive scan: deg[100000] -> rowptr (+cursor copy)
// ---------------------------------------------------------------------------
__global__ __launch_bounds__(1024) void scan1_kernel(
    const int* __restrict__ deg, int* __restrict__ rowptr,
    int* __restrict__ bsums, int n) {
    __shared__ int buf[1024];
    int i = blockIdx.x * 1024 + threadIdx.x;
    int v = (i < n) ? deg[i] : 0;
    buf[threadIdx.x] = v;
    __syncthreads();
    for (int off = 1; off < 1024; off <<= 1) {
        int t = (threadIdx.x >= off) ? buf[threadIdx.x - off] : 0;
        __syncthreads();
        if (threadIdx.x >= off) buf[threadIdx.x] += t;
        __syncthreads();
    }
    if (i < n) rowptr[i] = buf[threadIdx.x] - v;   // block-local exclusive
    if (threadIdx.x == 1023) bsums[blockIdx.x] = buf[1023];
}

__global__ __launch_bounds__(128) void scan2_kernel(int* __restrict__ bsums,
                                                    int nb) {
    __shared__ int buf[128];
    int v = (threadIdx.x < nb) ? bsums[threadIdx.x] : 0;
    buf[threadIdx.x] = v;
    __syncthreads();
    for (int off = 1; off < 128; off <<= 1) {
        int t = (threadIdx.x >= off) ? buf[threadIdx.x - off] : 0;
        __syncthreads();
        if (threadIdx.x >= off) buf[threadIdx.x] += t;
        __syncthreads();
    }
    if (threadIdx.x < nb) bsums[threadIdx.x] = buf[threadIdx.x] - v;  // excl
}

__global__ __launch_bounds__(1024) void scan3_kernel(
    int* __restrict__ rowptr, const int* __restrict__ bsums,
    int* __restrict__ cursor, int n, int nE) {
    int i = blockIdx.x * 1024 + threadIdx.x;
    if (i < n) {
        int r = rowptr[i] + bsums[blockIdx.x];
        rowptr[i] = r;
        cursor[i] = r;
    }
    if (i == 0) rowptr[n] = nE;
}

// ---------------------------------------------------------------------------
// CSR fill, XCD-partitioned. The naive version wrote 105 MB to HBM for a
// 6.4 MB col array (random 4B stores -> sparse dirty-byte-mask writebacks
// from 8 non-coherent L2s; dur 130 us == WRITE_SIZE/882 GB/s). Here block b
// handles only dst range (b&7): each ~800 KB col range is written by one
// XCD, stays L2-resident, lines fill densely -> one dense writeback.
// ---------------------------------------------------------------------------
__global__ __launch_bounds__(256) void csr_fill_part_kernel(
    const int* __restrict__ src,
    const int* __restrict__ dst,
    int* __restrict__ cursor,
    int* __restrict__ col, int nE) {
    const int g = blockIdx.x & (NGROUPS - 1);
    const int chunk = blockIdx.x >> 3;
    const int base = chunk * EPB;
    const unsigned lo = (unsigned)(g * NODES_PER_GROUP);
    for (int i = threadIdx.x; i < EPB; i += 256) {
        int e = base + i;
        if (e >= nE) break;
        int d = dst[e];
        if ((unsigned)(d - lo) < (unsigned)NODES_PER_GROUP) {
            int p = atomicAdd(&cursor[d], 1);
            col[p] = src[e];
        }
    }
}

// ---------------------------------------------------------------------------
// Gather-side mean aggregation. One wave (64 lanes) per node; each lane owns
// 2 channels (float2, 8B/lane -> 512B coalesced row read). No float atomics.
// X (51.2 MB) is L3-resident. Unroll x4 for load-chain ILP.
// ---------------------------------------------------------------------------
__global__ __launch_bounds__(256) void aggregate_mean_kernel(
    const float* __restrict__ X,
    const int* __restrict__ rowptr,
    const int* __restrict__ col,
    float* __restrict__ mean) {
    int node = (int)((blockIdx.x * blockDim.x + threadIdx.x) >> 6);
    int lane = threadIdx.x & 63;
    if (node >= N_NODES) return;
    int beg = rowptr[node];
    int end = rowptr[node + 1];
    float a0x = 0.f, a0y = 0.f, a1x = 0.f, a1y = 0.f;
    int p = beg;
    for (; p + 3 < end; p += 4) {
        int s0 = col[p];
        int s1 = col[p + 1];
        int s2 = col[p + 2];
        int s3 = col[p + 3];
        float2 v0 = ((const float2*)(X + (size_t)s0 * D))[lane];
        float2 v1 = ((const float2*)(X + (size_t)s1 * D))[lane];
        float2 v2 = ((const float2*)(X + (size_t)s2 * D))[lane];
        float2 v3 = ((const float2*)(X + (size_t)s3 * D))[lane];
        a0x += v0.x + v1.x;
        a0y += v0.y + v1.y;
        a1x += v2.x + v3.x;
        a1y += v2.y + v3.y;
    }
    for (; p < end; ++p) {
        int s = col[p];
        float2 v = ((const float2*)(X + (size_t)s * D))[lane];
        a0x += v.x;
        a0y += v.y;
    }
    int dg = end - beg;
    float invd = 1.0f / (float)(dg > 1 ? dg : 1);
    float2 o;
    o.x = (a0x + a1x) * invd;
    o.y = (a0y + a1y) * invd;
    ((float2*)(mean + (size_t)node * D))[lane] = o;
}

// ---------------------------------------------------------------------------
// Fused SAGE GEMM:  Out = relu(mean @ Wl + bias + Self @ Wr)
// [N,256] @ [256,128]: K-loop 0..255, first half (mean, Wl), second half
// (Self, Wr). Block tile 128x128, per-thread 8x8 as split column pair
// {4tx..4tx+3, 64+4tx..+3} (16B LDS lane stride -> all 32 banks). Safe for
// Amean == Out (in-place): each block reads only its own output rows, all
// reads precede its stores.
// ---------------------------------------------------------------------------
#define BM 128
#define BK 32

__global__ __launch_bounds__(256) void sage_gemm_kernel(
    const float* __restrict__ Amean,   // [N,128]
    const float* __restrict__ Aself,   // [N,128]
    const float* __restrict__ Wl,      // [128,128] row-major (k, j)
    const float* __restrict__ Wr,      // [128,128]
    const float* __restrict__ bias,    // [128]
    float* __restrict__ Out,           // [N,128]
    int nrows) {
    __shared__ float As[BM][BK + 4];    // stride 36 floats
    __shared__ float Bs[BK][132];       // stride 132 floats

    const int tid = threadIdx.x;
    const int row0 = blockIdx.x * BM;
    const int tx = tid & 15;    // column pair {4tx.., 64+4tx..}
    const int ty = tid >> 4;    // rows 8*ty .. 8*ty+7

    float acc[8][8];
#pragma unroll
    for (int i = 0; i < 8; i++)
#pragma unroll
        for (int j = 0; j < 8; j++) acc[i][j] = 0.f;

    for (int step = 0; step < 8; ++step) {
        const int k0 = step * BK;
        const float* A = (k0 < 128) ? Amean : Aself;
        const float* W = (k0 < 128) ? Wl : Wr;
        const int kc = k0 & 127;

        // stage A tile: each thread 16 consecutive floats (4x float4)
        {
            int r = tid >> 1;
            int kk0 = (tid & 1) * 16;
            int gr = row0 + r;
            if (gr >= nrows) gr = nrows - 1;
            const float4* srcp = (const float4*)(A + (size_t)gr * D + kc + kk0);
#pragma unroll
            for (int q = 0; q < 4; q++) {
                float4 v = srcp[q];
                *(float4*)&As[r][kk0 + 4 * q] = v;
            }
        }
        // stage B tile
        {
            int kk = tid >> 3;
            int c = tid & 7;
            const float4* srcp = (const float4*)(W + (size_t)(kc + kk) * D);
#pragma unroll
            for (int q = 0; q < 4; q++) {
                float4 v = srcp[c + 8 * q];
                *(float4*)&Bs[kk][(c + 8 * q) * 4] = v;
            }
        }
        __syncthreads();

#pragma unroll
        for (int kk = 0; kk < BK; ++kk) {
            float a[8], b[8];
#pragma unroll
            for (int i = 0; i < 8; i++) a[i] = As[ty * 8 + i][kk];
            float4 b0 = *(const float4*)&Bs[kk][tx * 4];
            float4 b1 = *(const float4*)&Bs[kk][64 + tx * 4];
            b[0] = b0.x; b[1] = b0.y; b[2] = b0.z; b[3] = b0.w;
            b[4] = b1.x; b[5] = b1.y; b[6] = b1.z; b[7] = b1.w;
#pragma unroll
            for (int i = 0; i < 8; i++)
#pragma unroll
                for (int j = 0; j < 8; j++) acc[i][j] += a[i] * b[j];
        }
        __syncthreads();
    }

    // epilogue: bias + relu + store (two float4 per row)
    float4 bv0 = *(const float4*)&bias[tx * 4];
    float4 bv1 = *(const float4*)&bias[64 + tx * 4];
#pragma unroll
    for (int i = 0; i < 8; i++) {
        int gr = row0 + ty * 8 + i;
        if (gr < nrows) {
            float4 o0, o1;
            o0.x = fmaxf(acc[i][0] + bv0.x, 0.f);
            o0.y = fmaxf(acc[i][1] + bv0.y, 0.f);
            o0.z = fmaxf(acc[i][2] + bv0.z, 0.f);
            o0.w = fmaxf(acc[i][3] + bv0.w, 0.f);
            o1.x = fmaxf(acc[i][4] + bv1.x, 0.f);
            o1.y = fmaxf(acc[i][5] + bv1.y, 0.f);
            o1.z = fmaxf(acc[i][6] + bv1.z, 0.f);
            o1.w = fmaxf(acc[i][7] + bv1.w, 0.f);
            *(float4*)(Out + (size_t)gr * D + tx * 4) = o0;
            *(float4*)(Out + (size_t)gr * D + 64 + tx * 4) = o1;
        }
    }
}

// ---------------------------------------------------------------------------
// Launch
// ---------------------------------------------------------------------------
extern "C" void kernel_launch(void* const* d_in, const int* in_sizes, int n_in,
                              void* d_out, int out_size, void* d_ws,
                              size_t ws_size, hipStream_t stream) {
    const float* x   = (const float*)d_in[0];
    const int*   ei  = (const int*)d_in[1];   // [2, E]: row0 = src, row1 = dst
    // d_in[2] edge_weight: unused by the reference
    const float* W0l = (const float*)d_in[3];
    const float* b0l = (const float*)d_in[4];
    const float* W0r = (const float*)d_in[5];
    const float* W2l = (const float*)d_in[6];
    const float* b2l = (const float*)d_in[7];
    const float* W2r = (const float*)d_in[8];

    const int* src = ei;
    const int* dst = ei + N_EDGES;

    float* fea = (float*)d_out;            // output 0: [N,128] (final)
    float* h   = (float*)d_out + NF;       // output 1 (mid feats): [N,128]
    // fea slot doubles as mean scratch: layer-0 mean lives there until the
    // layer-0 GEMM consumes it; layer-1 GEMM runs in place (block-exclusive
    // rows => safe).
    float* meanbuf = fea;

    // workspace: ints only, ~7.6 MB
    char* ws = (char*)d_ws;
    int* deg    = (int*)ws;                    //   400,000 B
    int* rowptr = (int*)(ws + 400000);         //   400,004 B
    int* bsums  = (int*)(ws + 800032);         //       512 B
    int* cursor = (int*)(ws + 800544);         //   400,000 B
    int* col    = (int*)(ws + 1200544);        // 6,400,000 B

    const int nScanBlocks = (N_NODES + 1023) / 1024;   // 98
    const int nChunks = (N_EDGES + EPB - 1) / EPB;     // 391

    // ---- build CSR (rebuilt every call; ws is re-poisoned) ----
    hipMemsetAsync(deg, 0, N_NODES * sizeof(int), stream);
    deg_count_part_kernel<<<nChunks * NGROUPS, 256, 0, stream>>>(dst, deg,
                                                                 N_EDGES);
    scan1_kernel<<<nScanBlocks, 1024, 0, stream>>>(deg, rowptr, bsums, N_NODES);
    scan2_kernel<<<1, 128, 0, stream>>>(bsums, nScanBlocks);
    scan3_kernel<<<nScanBlocks, 1024, 0, stream>>>(rowptr, bsums, cursor,
                                                   N_NODES, N_EDGES);
    csr_fill_part_kernel<<<nChunks * NGROUPS, 256, 0, stream>>>(src, dst,
                                                                cursor, col,
                                                                N_EDGES);

    const int aggGrid = (N_NODES * 64 + 255) / 256;      // one wave per node
    const int gemmGrid = (N_NODES + BM - 1) / BM;

    // ---- layer 0: h = relu(mean(x) @ W0l + b0l + x @ W0r) ----
    aggregate_mean_kernel<<<aggGrid, 256, 0, stream>>>(x, rowptr, col, meanbuf);
    sage_gemm_kernel<<<gemmGrid, 256, 0, stream>>>(meanbuf, x, W0l, W0r, b0l, h,
                                                   N_NODES);

    // ---- layer 1: fea = relu(mean(h) @ W2l + b2l + h @ W2r), in place ----
    aggregate_mean_kernel<<<aggGrid, 256, 0, stream>>>(h, rowptr, col, meanbuf);
    sage_gemm_kernel<<<gemmGrid, 256, 0, stream>>>(meanbuf, h, W2l, W2r, b2l,
                                                   fea, N_NODES);
}

// Round 10
// 644.628 us; speedup vs baseline: 1.1710x; 1.1087x over previous
//
#include <hip/hip_runtime.h>
#include <hip/hip_bf16.h>

#define N_NODES 100000
#define N_EDGES 1600000
#define D 128
#define NF (N_NODES * D)   // floats per feature matrix

#define NGROUPS 8
#define NODES_PER_GROUP ((N_NODES + NGROUPS - 1) / NGROUPS)   // 12500
#define EPB 4096    // edges per chunk for partitioned passes

static __device__ __forceinline__ unsigned short f32_to_bf16_rne(float f) {
    unsigned u = __float_as_uint(f);
    unsigned lsb = (u >> 16) & 1u;
    u += 0x7fffu + lsb;                 // round-to-nearest-even
    return (unsigned short)(u >> 16);
}

// ---------------------------------------------------------------------------
// f32 -> packed bf16 conversion (8 elems/thread; n must be divisible by 8)
// ---------------------------------------------------------------------------
__global__ __launch_bounds__(256) void convert_bf16_kernel(
    const float* __restrict__ in, unsigned* __restrict__ out, int n8) {
    int i = blockIdx.x * blockDim.x + threadIdx.x;
    if (i >= n8) return;
    const float4* p = (const float4*)(in + (size_t)i * 8);
    float4 a = p[0], b = p[1];
    uint4 o;
    o.x = (unsigned)f32_to_bf16_rne(a.x) | ((unsigned)f32_to_bf16_rne(a.y) << 16);
    o.y = (unsigned)f32_to_bf16_rne(a.z) | ((unsigned)f32_to_bf16_rne(a.w) << 16);
    o.z = (unsigned)f32_to_bf16_rne(b.x) | ((unsigned)f32_to_bf16_rne(b.y) << 16);
    o.w = (unsigned)f32_to_bf16_rne(b.z) | ((unsigned)f32_to_bf16_rne(b.w) << 16);
    ((uint4*)out)[i] = o;
}

// ---------------------------------------------------------------------------
// In-degree count, XCD-partitioned (r2 profile: confines atomic targets to
// one 50 KB range per XCD).
// ---------------------------------------------------------------------------
__global__ __launch_bounds__(256) void deg_count_part_kernel(
    const int* __restrict__ dst, int* __restrict__ deg, int nE) {
    const int g = blockIdx.x & (NGROUPS - 1);
    const int chunk = blockIdx.x >> 3;
    const int base = chunk * EPB;
    const unsigned lo = (unsigned)(g * NODES_PER_GROUP);
    for (int i = threadIdx.x; i < EPB; i += 256) {
        int e = base + i;
        if (e >= nE) break;
        int d = dst[e];
        if ((unsigned)(d - lo) < (unsigned)NODES_PER_GROUP) {
            atomicAdd(&deg[d], 1);
        }
    }
}

// ---------------------------------------------------------------------------
// Hierarchical exclusive scan: deg[100000] -> rowptr (+cursor copy)
// ---------------------------------------------------------------------------
__global__ __launch_bounds__(1024) void scan1_kernel(
    const int* __restrict__ deg, int* __restrict__ rowptr,
    int* __restrict__ bsums, int n) {
    __shared__ int buf[1024];
    int i = blockIdx.x * 1024 + threadIdx.x;
    int v = (i < n) ? deg[i] : 0;
    buf[threadIdx.x] = v;
    __syncthreads();
    for (int off = 1; off < 1024; off <<= 1) {
        int t = (threadIdx.x >= off) ? buf[threadIdx.x - off] : 0;
        __syncthreads();
        if (threadIdx.x >= off) buf[threadIdx.x] += t;
        __syncthreads();
    }
    if (i < n) rowptr[i] = buf[threadIdx.x] - v;   // block-local exclusive
    if (threadIdx.x == 1023) bsums[blockIdx.x] = buf[1023];
}

__global__ __launch_bounds__(128) void scan2_kernel(int* __restrict__ bsums,
                                                    int nb) {
    __shared__ int buf[128];
    int v = (threadIdx.x < nb) ? bsums[threadIdx.x] : 0;
    buf[threadIdx.x] = v;
    __syncthreads();
    for (int off = 1; off < 128; off <<= 1) {
        int t = (threadIdx.x >= off) ? buf[threadIdx.x - off] : 0;
        __syncthreads();
        if (threadIdx.x >= off) buf[threadIdx.x] += t;
        __syncthreads();
    }
    if (threadIdx.x < nb) bsums[threadIdx.x] = buf[threadIdx.x] - v;  // excl
}

__global__ __launch_bounds__(1024) void scan3_kernel(
    int* __restrict__ rowptr, const int* __restrict__ bsums,
    int* __restrict__ cursor, int n, int nE) {
    int i = blockIdx.x * 1024 + threadIdx.x;
    if (i < n) {
        int r = rowptr[i] + bsums[blockIdx.x];
        rowptr[i] = r;
        cursor[i] = r;
    }
    if (i == 0) rowptr[n] = nE;
}

// ---------------------------------------------------------------------------
// CSR fill, XCD-partitioned (r2->r6: WRITE_SIZE 105 MB -> off top-5).
// ---------------------------------------------------------------------------
__global__ __launch_bounds__(256) void csr_fill_part_kernel(
    const int* __restrict__ src,
    const int* __restrict__ dst,
    int* __restrict__ cursor,
    int* __restrict__ col, int nE) {
    const int g = blockIdx.x & (NGROUPS - 1);
    const int chunk = blockIdx.x >> 3;
    const int base = chunk * EPB;
    const unsigned lo = (unsigned)(g * NODES_PER_GROUP);
    for (int i = threadIdx.x; i < EPB; i += 256) {
        int e = base + i;
        if (e >= nE) break;
        int d = dst[e];
        if ((unsigned)(d - lo) < (unsigned)NODES_PER_GROUP) {
            int p = atomicAdd(&cursor[d], 1);
            col[p] = src[e];
        }
    }
}

// ---------------------------------------------------------------------------
// Mean aggregation, bf16-gather variant. r6 profile: f32 gather is L2-miss
// bound (FETCH 377 MB @ 3.46 TB/s = the 126 us). bf16 rows are 256 B: one
// uint (2 channels) per lane, halving fabric bytes; accumulate f32; write
// f32 mean. bf16->f32 is a 16-bit shift (exact).
// ---------------------------------------------------------------------------
__global__ __launch_bounds__(256) void aggregate_mean_bf16_kernel(
    const unsigned short* __restrict__ Xb,
    const int* __restrict__ rowptr,
    const int* __restrict__ col,
    float* __restrict__ mean) {
    int node = (int)((blockIdx.x * blockDim.x + threadIdx.x) >> 6);
    int lane = threadIdx.x & 63;
    if (node >= N_NODES) return;
    int beg = rowptr[node];
    int end = rowptr[node + 1];
    float a0x = 0.f, a0y = 0.f, a1x = 0.f, a1y = 0.f;
    int p = beg;
    for (; p + 3 < end; p += 4) {
        int s0 = col[p];
        int s1 = col[p + 1];
        int s2 = col[p + 2];
        int s3 = col[p + 3];
        unsigned v0 = ((const unsigned*)(Xb + (size_t)s0 * D))[lane];
        unsigned v1 = ((const unsigned*)(Xb + (size_t)s1 * D))[lane];
        unsigned v2 = ((const unsigned*)(Xb + (size_t)s2 * D))[lane];
        unsigned v3 = ((const unsigned*)(Xb + (size_t)s3 * D))[lane];
        a0x += __uint_as_float(v0 << 16) + __uint_as_float(v1 << 16);
        a0y += __uint_as_float(v0 & 0xffff0000u) + __uint_as_float(v1 & 0xffff0000u);
        a1x += __uint_as_float(v2 << 16) + __uint_as_float(v3 << 16);
        a1y += __uint_as_float(v2 & 0xffff0000u) + __uint_as_float(v3 & 0xffff0000u);
    }
    for (; p < end; ++p) {
        int s = col[p];
        unsigned v = ((const unsigned*)(Xb + (size_t)s * D))[lane];
        a0x += __uint_as_float(v << 16);
        a0y += __uint_as_float(v & 0xffff0000u);
    }
    int dg = end - beg;
    float invd = 1.0f / (float)(dg > 1 ? dg : 1);
    float2 o;
    o.x = (a0x + a1x) * invd;
    o.y = (a0y + a1y) * invd;
    ((float2*)(mean + (size_t)node * D))[lane] = o;
}

// ---------------------------------------------------------------------------
// Mean aggregation, f32 fallback (used when ws_size can't hold the bf16 buf)
// ---------------------------------------------------------------------------
__global__ __launch_bounds__(256) void aggregate_mean_kernel(
    const float* __restrict__ X,
    const int* __restrict__ rowptr,
    const int* __restrict__ col,
    float* __restrict__ mean) {
    int node = (int)((blockIdx.x * blockDim.x + threadIdx.x) >> 6);
    int lane = threadIdx.x & 63;
    if (node >= N_NODES) return;
    int beg = rowptr[node];
    int end = rowptr[node + 1];
    float a0x = 0.f, a0y = 0.f, a1x = 0.f, a1y = 0.f;
    int p = beg;
    for (; p + 3 < end; p += 4) {
        int s0 = col[p];
        int s1 = col[p + 1];
        int s2 = col[p + 2];
        int s3 = col[p + 3];
        float2 v0 = ((const float2*)(X + (size_t)s0 * D))[lane];
        float2 v1 = ((const float2*)(X + (size_t)s1 * D))[lane];
        float2 v2 = ((const float2*)(X + (size_t)s2 * D))[lane];
        float2 v3 = ((const float2*)(X + (size_t)s3 * D))[lane];
        a0x += v0.x + v1.x;
        a0y += v0.y + v1.y;
        a1x += v2.x + v3.x;
        a1y += v2.y + v3.y;
    }
    for (; p < end; ++p) {
        int s = col[p];
        float2 v = ((const float2*)(X + (size_t)s * D))[lane];
        a0x += v.x;
        a0y += v.y;
    }
    int dg = end - beg;
    float invd = 1.0f / (float)(dg > 1 ? dg : 1);
    float2 o;
    o.x = (a0x + a1x) * invd;
    o.y = (a0y + a1y) * invd;
    ((float2*)(mean + (size_t)node * D))[lane] = o;
}

// ---------------------------------------------------------------------------
// Fused SAGE GEMM:  Out = relu(mean @ Wl + bias + Self @ Wr)
// [N,256] @ [256,128]. Optionally also emits bf16 copy of Out (for the next
// layer's gather). Safe for Amean == Out (block-exclusive rows; all A reads
// precede epilogue stores).
// ---------------------------------------------------------------------------
#define BM 128
#define BK 32

__global__ __launch_bounds__(256) void sage_gemm_kernel(
    const float* __restrict__ Amean,   // [N,128]
    const float* __restrict__ Aself,   // [N,128]
    const float* __restrict__ Wl,      // [128,128] row-major (k, j)
    const float* __restrict__ Wr,      // [128,128]
    const float* __restrict__ bias,    // [128]
    float* __restrict__ Out,           // [N,128]
    unsigned short* __restrict__ OutBf,  // [N,128] bf16 or nullptr
    int nrows) {
    __shared__ float As[BM][BK + 4];    // stride 36 floats
    __shared__ float Bs[BK][132];       // stride 132 floats

    const int tid = threadIdx.x;
    const int row0 = blockIdx.x * BM;
    const int tx = tid & 15;    // column pair {4tx.., 64+4tx..}
    const int ty = tid >> 4;    // rows 8*ty .. 8*ty+7

    float acc[8][8];
#pragma unroll
    for (int i = 0; i < 8; i++)
#pragma unroll
        for (int j = 0; j < 8; j++) acc[i][j] = 0.f;

    for (int step = 0; step < 8; ++step) {
        const int k0 = step * BK;
        const float* A = (k0 < 128) ? Amean : Aself;
        const float* W = (k0 < 128) ? Wl : Wr;
        const int kc = k0 & 127;

        // stage A tile: each thread 16 consecutive floats (4x float4)
        {
            int r = tid >> 1;
            int kk0 = (tid & 1) * 16;
            int gr = row0 + r;
            if (gr >= nrows) gr = nrows - 1;
            const float4* srcp = (const float4*)(A + (size_t)gr * D + kc + kk0);
#pragma unroll
            for (int q = 0; q < 4; q++) {
                float4 v = srcp[q];
                *(float4*)&As[r][kk0 + 4 * q] = v;
            }
        }
        // stage B tile
        {
            int kk = tid >> 3;
            int c = tid & 7;
            const float4* srcp = (const float4*)(W + (size_t)(kc + kk) * D);
#pragma unroll
            for (int q = 0; q < 4; q++) {
                float4 v = srcp[c + 8 * q];
                *(float4*)&Bs[kk][(c + 8 * q) * 4] = v;
            }
        }
        __syncthreads();

#pragma unroll
        for (int kk = 0; kk < BK; ++kk) {
            float a[8], b[8];
#pragma unroll
            for (int i = 0; i < 8; i++) a[i] = As[ty * 8 + i][kk];
            float4 b0 = *(const float4*)&Bs[kk][tx * 4];
            float4 b1 = *(const float4*)&Bs[kk][64 + tx * 4];
            b[0] = b0.x; b[1] = b0.y; b[2] = b0.z; b[3] = b0.w;
            b[4] = b1.x; b[5] = b1.y; b[6] = b1.z; b[7] = b1.w;
#pragma unroll
            for (int i = 0; i < 8; i++)
#pragma unroll
                for (int j = 0; j < 8; j++) acc[i][j] += a[i] * b[j];
        }
        __syncthreads();
    }

    // epilogue: bias + relu + store (two float4 per row, + optional bf16)
    float4 bv0 = *(const float4*)&bias[tx * 4];
    float4 bv1 = *(const float4*)&bias[64 + tx * 4];
#pragma unroll
    for (int i = 0; i < 8; i++) {
        int gr = row0 + ty * 8 + i;
        if (gr < nrows) {
            float4 o0, o1;
            o0.x = fmaxf(acc[i][0] + bv0.x, 0.f);
            o0.y = fmaxf(acc[i][1] + bv0.y, 0.f);
            o0.z = fmaxf(acc[i][2] + bv0.z, 0.f);
            o0.w = fmaxf(acc[i][3] + bv0.w, 0.f);
            o1.x = fmaxf(acc[i][4] + bv1.x, 0.f);
            o1.y = fmaxf(acc[i][5] + bv1.y, 0.f);
            o1.z = fmaxf(acc[i][6] + bv1.z, 0.f);
            o1.w = fmaxf(acc[i][7] + bv1.w, 0.f);
            *(float4*)(Out + (size_t)gr * D + tx * 4) = o0;
            *(float4*)(Out + (size_t)gr * D + 64 + tx * 4) = o1;
            if (OutBf) {
                uint2 p0, p1;
                p0.x = (unsigned)f32_to_bf16_rne(o0.x) |
                       ((unsigned)f32_to_bf16_rne(o0.y) << 16);
                p0.y = (unsigned)f32_to_bf16_rne(o0.z) |
                       ((unsigned)f32_to_bf16_rne(o0.w) << 16);
                p1.x = (unsigned)f32_to_bf16_rne(o1.x) |
                       ((unsigned)f32_to_bf16_rne(o1.y) << 16);
                p1.y = (unsigned)f32_to_bf16_rne(o1.z) |
                       ((unsigned)f32_to_bf16_rne(o1.w) << 16);
                *(uint2*)(OutBf + (size_t)gr * D + tx * 4) = p0;
                *(uint2*)(OutBf + (size_t)gr * D + 64 + tx * 4) = p1;
            }
        }
    }
}

// ---------------------------------------------------------------------------
// Launch
// ---------------------------------------------------------------------------
extern "C" void kernel_launch(void* const* d_in, const int* in_sizes, int n_in,
                              void* d_out, int out_size, void* d_ws,
                              size_t ws_size, hipStream_t stream) {
    const float* x   = (const float*)d_in[0];
    const int*   ei  = (const int*)d_in[1];   // [2, E]: row0 = src, row1 = dst
    // d_in[2] edge_weight: unused by the reference
    const float* W0l = (const float*)d_in[3];
    const float* b0l = (const float*)d_in[4];
    const float* W0r = (const float*)d_in[5];
    const float* W2l = (const float*)d_in[6];
    const float* b2l = (const float*)d_in[7];
    const float* W2r = (const float*)d_in[8];

    const int* src = ei;
    const int* dst = ei + N_EDGES;

    float* fea = (float*)d_out;            // output 0: [N,128] (final)
    float* h   = (float*)d_out + NF;       // output 1 (mid feats): [N,128]
    float* meanbuf = fea;                  // fea slot doubles as mean scratch

    // workspace layout
    char* ws = (char*)d_ws;
    int* deg    = (int*)ws;                    //   400,000 B
    int* rowptr = (int*)(ws + 400000);         //   400,004 B
    int* bsums  = (int*)(ws + 800032);         //       512 B
    int* cursor = (int*)(ws + 800544);         //   400,000 B
    int* col    = (int*)(ws + 1200544);        // 6,400,000 B -> end 7,600,544
    unsigned short* xb = (unsigned short*)(ws + 7600640);  // 25,600,000 B bf16
    const bool use_bf16 = (ws_size >= (size_t)33200640);

    const int nScanBlocks = (N_NODES + 1023) / 1024;   // 98
    const int nChunks = (N_EDGES + EPB - 1) / EPB;     // 391

    // ---- build CSR (rebuilt every call; ws is re-poisoned) ----
    hipMemsetAsync(deg, 0, N_NODES * sizeof(int), stream);
    deg_count_part_kernel<<<nChunks * NGROUPS, 256, 0, stream>>>(dst, deg,
                                                                 N_EDGES);
    scan1_kernel<<<nScanBlocks, 1024, 0, stream>>>(deg, rowptr, bsums, N_NODES);
    scan2_kernel<<<1, 128, 0, stream>>>(bsums, nScanBlocks);
    scan3_kernel<<<nScanBlocks, 1024, 0, stream>>>(rowptr, bsums, cursor,
                                                   N_NODES, N_EDGES);
    csr_fill_part_kernel<<<nChunks * NGROUPS, 256, 0, stream>>>(src, dst,
                                                                cursor, col,
                                                                N_EDGES);

    const int aggGrid = (N_NODES * 64 + 255) / 256;      // one wave per node
    const int gemmGrid = (N_NODES + BM - 1) / BM;

    if (use_bf16) {
        // x -> bf16 (one-shot); h_bf16 is emitted by the layer-0 GEMM into
        // the same buffer (x_bf16 is dead by then; stream-ordered).
        convert_bf16_kernel<<<(NF / 8 + 255) / 256, 256, 0, stream>>>(
            x, (unsigned*)xb, NF / 8);

        // ---- layer 0 ----
        aggregate_mean_bf16_kernel<<<aggGrid, 256, 0, stream>>>(xb, rowptr,
                                                                col, meanbuf);
        sage_gemm_kernel<<<gemmGrid, 256, 0, stream>>>(meanbuf, x, W0l, W0r,
                                                       b0l, h, xb, N_NODES);

        // ---- layer 1 (in place on fea) ----
        aggregate_mean_bf16_kernel<<<aggGrid, 256, 0, stream>>>(xb, rowptr,
                                                                col, meanbuf);
        sage_gemm_kernel<<<gemmGrid, 256, 0, stream>>>(meanbuf, h, W2l, W2r,
                                                       b2l, fea, (unsigned short*)nullptr,
                                                       N_NODES);
    } else {
        // ---- f32 fallback (identical to r6-passed path) ----
        aggregate_mean_kernel<<<aggGrid, 256, 0, stream>>>(x, rowptr, col,
                                                           meanbuf);
        sage_gemm_kernel<<<gemmGrid, 256, 0, stream>>>(meanbuf, x, W0l, W0r,
                                                       b0l, h, (unsigned short*)nullptr,
                                                       N_NODES);
        aggregate_mean_kernel<<<aggGrid, 256, 0, stream>>>(h, rowptr, col,
                                                           meanbuf);
        sage_gemm_kernel<<<gemmGrid, 256, 0, stream>>>(meanbuf, h, W2l, W2r,
                                                       b2l, fea, (unsigned short*)nullptr,
                                                       N_NODES);
    }
}

// Round 11
// 627.489 us; speedup vs baseline: 1.2030x; 1.0273x over previous
//
#include <hip/hip_runtime.h>
#include <hip/hip_bf16.h>

#define N_NODES 100000
#define N_EDGES 1600000
#define D 128
#define NF (N_NODES * D)   // floats per feature matrix

#define NGROUPS 8
#define NODES_PER_GROUP ((N_NODES + NGROUPS - 1) / NGROUPS)   // 12500
#define EPB 4096    // edges per chunk for partitioned passes

static __device__ __forceinline__ unsigned short f32_to_bf16_rne(float f) {
    unsigned u = __float_as_uint(f);
    unsigned lsb = (u >> 16) & 1u;
    u += 0x7fffu + lsb;                 // round-to-nearest-even
    return (unsigned short)(u >> 16);
}

// ---------------------------------------------------------------------------
// f32 -> packed bf16 conversion (8 elems/thread; n must be divisible by 8)
// ---------------------------------------------------------------------------
__global__ __launch_bounds__(256) void convert_bf16_kernel(
    const float* __restrict__ in, unsigned* __restrict__ out, int n8) {
    int i = blockIdx.x * blockDim.x + threadIdx.x;
    if (i >= n8) return;
    const float4* p = (const float4*)(in + (size_t)i * 8);
    float4 a = p[0], b = p[1];
    uint4 o;
    o.x = (unsigned)f32_to_bf16_rne(a.x) | ((unsigned)f32_to_bf16_rne(a.y) << 16);
    o.y = (unsigned)f32_to_bf16_rne(a.z) | ((unsigned)f32_to_bf16_rne(a.w) << 16);
    o.z = (unsigned)f32_to_bf16_rne(b.x) | ((unsigned)f32_to_bf16_rne(b.y) << 16);
    o.w = (unsigned)f32_to_bf16_rne(b.z) | ((unsigned)f32_to_bf16_rne(b.w) << 16);
    ((uint4*)out)[i] = o;
}

// ---------------------------------------------------------------------------
// In-degree count, XCD-partitioned (r2 profile: confines atomic targets to
// one 50 KB range per XCD).
// ---------------------------------------------------------------------------
__global__ __launch_bounds__(256) void deg_count_part_kernel(
    const int* __restrict__ dst, int* __restrict__ deg, int nE) {
    const int g = blockIdx.x & (NGROUPS - 1);
    const int chunk = blockIdx.x >> 3;
    const int base = chunk * EPB;
    const unsigned lo = (unsigned)(g * NODES_PER_GROUP);
    for (int i = threadIdx.x; i < EPB; i += 256) {
        int e = base + i;
        if (e >= nE) break;
        int d = dst[e];
        if ((unsigned)(d - lo) < (unsigned)NODES_PER_GROUP) {
            atomicAdd(&deg[d], 1);
        }
    }
}

// ---------------------------------------------------------------------------
// Hierarchical exclusive scan: deg[100000] -> rowptr (+cursor copy)
// ---------------------------------------------------------------------------
__global__ __launch_bounds__(1024) void scan1_kernel(
    const int* __restrict__ deg, int* __restrict__ rowptr,
    int* __restrict__ bsums, int n) {
    __shared__ int buf[1024];
    int i = blockIdx.x * 1024 + threadIdx.x;
    int v = (i < n) ? deg[i] : 0;
    buf[threadIdx.x] = v;
    __syncthreads();
    for (int off = 1; off < 1024; off <<= 1) {
        int t = (threadIdx.x >= off) ? buf[threadIdx.x - off] : 0;
        __syncthreads();
        if (threadIdx.x >= off) buf[threadIdx.x] += t;
        __syncthreads();
    }
    if (i < n) rowptr[i] = buf[threadIdx.x] - v;   // block-local exclusive
    if (threadIdx.x == 1023) bsums[blockIdx.x] = buf[1023];
}

__global__ __launch_bounds__(128) void scan2_kernel(int* __restrict__ bsums,
                                                    int nb) {
    __shared__ int buf[128];
    int v = (threadIdx.x < nb) ? bsums[threadIdx.x] : 0;
    buf[threadIdx.x] = v;
    __syncthreads();
    for (int off = 1; off < 128; off <<= 1) {
        int t = (threadIdx.x >= off) ? buf[threadIdx.x - off] : 0;
        __syncthreads();
        if (threadIdx.x >= off) buf[threadIdx.x] += t;
        __syncthreads();
    }
    if (threadIdx.x < nb) bsums[threadIdx.x] = buf[threadIdx.x] - v;  // excl
}

__global__ __launch_bounds__(1024) void scan3_kernel(
    int* __restrict__ rowptr, const int* __restrict__ bsums,
    int* __restrict__ cursor, int n, int nE) {
    int i = blockIdx.x * 1024 + threadIdx.x;
    if (i < n) {
        int r = rowptr[i] + bsums[blockIdx.x];
        rowptr[i] = r;
        cursor[i] = r;
    }
    if (i == 0) rowptr[n] = nE;
}

// ---------------------------------------------------------------------------
// CSR fill, XCD-partitioned (r2->r6: WRITE_SIZE 105 MB -> off top-5).
// ---------------------------------------------------------------------------
__global__ __launch_bounds__(256) void csr_fill_part_kernel(
    const int* __restrict__ src,
    const int* __restrict__ dst,
    int* __restrict__ cursor,
    int* __restrict__ col, int nE) {
    const int g = blockIdx.x & (NGROUPS - 1);
    const int chunk = blockIdx.x >> 3;
    const int base = chunk * EPB;
    const unsigned lo = (unsigned)(g * NODES_PER_GROUP);
    for (int i = threadIdx.x; i < EPB; i += 256) {
        int e = base + i;
        if (e >= nE) break;
        int d = dst[e];
        if ((unsigned)(d - lo) < (unsigned)NODES_PER_GROUP) {
            int p = atomicAdd(&cursor[d], 1);
            col[p] = src[e];
        }
    }
}

// ---------------------------------------------------------------------------
// Mean aggregation, bf16-gather (validated r10: absmax 0.03125, passed;
// dropped agg off the top-5).
// ---------------------------------------------------------------------------
__global__ __launch_bounds__(256) void aggregate_mean_bf16_kernel(
    const unsigned short* __restrict__ Xb,
    const int* __restrict__ rowptr,
    const int* __restrict__ col,
    float* __restrict__ mean) {
    int node = (int)((blockIdx.x * blockDim.x + threadIdx.x) >> 6);
    int lane = threadIdx.x & 63;
    if (node >= N_NODES) return;
    int beg = rowptr[node];
    int end = rowptr[node + 1];
    float a0x = 0.f, a0y = 0.f, a1x = 0.f, a1y = 0.f;
    int p = beg;
    for (; p + 3 < end; p += 4) {
        int s0 = col[p];
        int s1 = col[p + 1];
        int s2 = col[p + 2];
        int s3 = col[p + 3];
        unsigned v0 = ((const unsigned*)(Xb + (size_t)s0 * D))[lane];
        unsigned v1 = ((const unsigned*)(Xb + (size_t)s1 * D))[lane];
        unsigned v2 = ((const unsigned*)(Xb + (size_t)s2 * D))[lane];
        unsigned v3 = ((const unsigned*)(Xb + (size_t)s3 * D))[lane];
        a0x += __uint_as_float(v0 << 16) + __uint_as_float(v1 << 16);
        a0y += __uint_as_float(v0 & 0xffff0000u) + __uint_as_float(v1 & 0xffff0000u);
        a1x += __uint_as_float(v2 << 16) + __uint_as_float(v3 << 16);
        a1y += __uint_as_float(v2 & 0xffff0000u) + __uint_as_float(v3 & 0xffff0000u);
    }
    for (; p < end; ++p) {
        int s = col[p];
        unsigned v = ((const unsigned*)(Xb + (size_t)s * D))[lane];
        a0x += __uint_as_float(v << 16);
        a0y += __uint_as_float(v & 0xffff0000u);
    }
    int dg = end - beg;
    float invd = 1.0f / (float)(dg > 1 ? dg : 1);
    float2 o;
    o.x = (a0x + a1x) * invd;
    o.y = (a0y + a1y) * invd;
    ((float2*)(mean + (size_t)node * D))[lane] = o;
}

// ---------------------------------------------------------------------------
// Mean aggregation, f32 fallback (used when ws_size can't hold the bf16 buf)
// ---------------------------------------------------------------------------
__global__ __launch_bounds__(256) void aggregate_mean_kernel(
    const float* __restrict__ X,
    const int* __restrict__ rowptr,
    const int* __restrict__ col,
    float* __restrict__ mean) {
    int node = (int)((blockIdx.x * blockDim.x + threadIdx.x) >> 6);
    int lane = threadIdx.x & 63;
    if (node >= N_NODES) return;
    int beg = rowptr[node];
    int end = rowptr[node + 1];
    float a0x = 0.f, a0y = 0.f, a1x = 0.f, a1y = 0.f;
    int p = beg;
    for (; p + 3 < end; p += 4) {
        int s0 = col[p];
        int s1 = col[p + 1];
        int s2 = col[p + 2];
        int s3 = col[p + 3];
        float2 v0 = ((const float2*)(X + (size_t)s0 * D))[lane];
        float2 v1 = ((const float2*)(X + (size_t)s1 * D))[lane];
        float2 v2 = ((const float2*)(X + (size_t)s2 * D))[lane];
        float2 v3 = ((const float2*)(X + (size_t)s3 * D))[lane];
        a0x += v0.x + v1.x;
        a0y += v0.y + v1.y;
        a1x += v2.x + v3.x;
        a1y += v2.y + v3.y;
    }
    for (; p < end; ++p) {
        int s = col[p];
        float2 v = ((const float2*)(X + (size_t)s * D))[lane];
        a0x += v.x;
        a0y += v.y;
    }
    int dg = end - beg;
    float invd = 1.0f / (float)(dg > 1 ? dg : 1);
    float2 o;
    o.x = (a0x + a1x) * invd;
    o.y = (a0y + a1y) * invd;
    ((float2*)(mean + (size_t)node * D))[lane] = o;
}

// ---------------------------------------------------------------------------
// Fused SAGE GEMM:  Out = relu(mean @ Wl + bias + Self @ Wr)
// r10 profile: 110.5 us, VALUBusy 45%, Occupancy 19% (grid 782 = 3 blk/CU,
// barrier-starved) + 8 scalar ds_read_b32/kk for the A column. Fix:
//  - BM 128 -> 64: grid 1563 (~6 blk/CU), LDS 25.6 KB (6 blk/CU fit).
//  - AsT[BK][68] k-major (272 B rows, 16B-aligned): A read per kk is ONE
//    ds_read_b128; staging is 8 scalar ds_write_b32, bank-free (2 lanes/bank).
// Inner loop: 3 LDS instr + 32 FMA. Same FMA order per output element ->
// bit-identical to r10 (absmax canary 0.03125). In-place safe (block reads
// only its own 64 rows; clamp targets its own last row).
// ---------------------------------------------------------------------------
#define BM 64
#define BK 32

__global__ __launch_bounds__(256) void sage_gemm_kernel(
    const float* __restrict__ Amean,   // [N,128]
    const float* __restrict__ Aself,   // [N,128]
    const float* __restrict__ Wl,      // [128,128] row-major (k, j)
    const float* __restrict__ Wr,      // [128,128]
    const float* __restrict__ bias,    // [128]
    float* __restrict__ Out,           // [N,128]
    unsigned short* __restrict__ OutBf,  // [N,128] bf16 or nullptr
    int nrows) {
    __shared__ float AsT[BK][68];       // k-major; stride 68 floats
    __shared__ float Bs[BK][132];       // stride 132 floats

    const int tid = threadIdx.x;
    const int row0 = blockIdx.x * BM;
    const int tx = tid & 15;    // column pair {4tx.., 64+4tx..}
    const int ty = tid >> 4;    // 0..15 -> rows 4*ty .. 4*ty+3

    float acc[4][8];
#pragma unroll
    for (int i = 0; i < 4; i++)
#pragma unroll
        for (int j = 0; j < 8; j++) acc[i][j] = 0.f;

    for (int step = 0; step < 8; ++step) {
        const float* A = (step < 4) ? Amean : Aself;
        const float* W = (step < 4) ? Wl : Wr;
        const int kc = (step & 3) * BK;

        // stage A transposed: r = tid&63 (row), kb = tid>>6 (k-octet)
        {
            int r = tid & 63;
            int kb = tid >> 6;              // 0..3 -> k = 8*kb .. 8*kb+7
            int gr = row0 + r;
            if (gr >= nrows) gr = nrows - 1;
            const float4* srcp = (const float4*)(A + (size_t)gr * D + kc + kb * 8);
            float4 v0 = srcp[0], v1 = srcp[1];
            int k0 = kb * 8;
            AsT[k0 + 0][r] = v0.x; AsT[k0 + 1][r] = v0.y;
            AsT[k0 + 2][r] = v0.z; AsT[k0 + 3][r] = v0.w;
            AsT[k0 + 4][r] = v1.x; AsT[k0 + 5][r] = v1.y;
            AsT[k0 + 6][r] = v1.z; AsT[k0 + 7][r] = v1.w;
        }
        // stage B tile
        {
            int kk = tid >> 3;
            int c = tid & 7;
            const float4* srcp = (const float4*)(W + (size_t)(kc + kk) * D);
#pragma unroll
            for (int q = 0; q < 4; q++) {
                float4 v = srcp[c + 8 * q];
                *(float4*)&Bs[kk][(c + 8 * q) * 4] = v;
            }
        }
        __syncthreads();

#pragma unroll
        for (int kk = 0; kk < BK; ++kk) {
            float4 av = *(const float4*)&AsT[kk][ty * 4];
            float4 b0 = *(const float4*)&Bs[kk][tx * 4];
            float4 b1 = *(const float4*)&Bs[kk][64 + tx * 4];
            float a[4] = {av.x, av.y, av.z, av.w};
            float b[8] = {b0.x, b0.y, b0.z, b0.w, b1.x, b1.y, b1.z, b1.w};
#pragma unroll
            for (int i = 0; i < 4; i++)
#pragma unroll
                for (int j = 0; j < 8; j++) acc[i][j] += a[i] * b[j];
        }
        __syncthreads();
    }

    // epilogue: bias + relu + store (two float4 per row, + optional bf16)
    float4 bv0 = *(const float4*)&bias[tx * 4];
    float4 bv1 = *(const float4*)&bias[64 + tx * 4];
#pragma unroll
    for (int i = 0; i < 4; i++) {
        int gr = row0 + ty * 4 + i;
        if (gr < nrows) {
            float4 o0, o1;
            o0.x = fmaxf(acc[i][0] + bv0.x, 0.f);
            o0.y = fmaxf(acc[i][1] + bv0.y, 0.f);
            o0.z = fmaxf(acc[i][2] + bv0.z, 0.f);
            o0.w = fmaxf(acc[i][3] + bv0.w, 0.f);
            o1.x = fmaxf(acc[i][4] + bv1.x, 0.f);
            o1.y = fmaxf(acc[i][5] + bv1.y, 0.f);
            o1.z = fmaxf(acc[i][6] + bv1.z, 0.f);
            o1.w = fmaxf(acc[i][7] + bv1.w, 0.f);
            *(float4*)(Out + (size_t)gr * D + tx * 4) = o0;
            *(float4*)(Out + (size_t)gr * D + 64 + tx * 4) = o1;
            if (OutBf) {
                uint2 p0, p1;
                p0.x = (unsigned)f32_to_bf16_rne(o0.x) |
                       ((unsigned)f32_to_bf16_rne(o0.y) << 16);
                p0.y = (unsigned)f32_to_bf16_rne(o0.z) |
                       ((unsigned)f32_to_bf16_rne(o0.w) << 16);
                p1.x = (unsigned)f32_to_bf16_rne(o1.x) |
                       ((unsigned)f32_to_bf16_rne(o1.y) << 16);
                p1.y = (unsigned)f32_to_bf16_rne(o1.z) |
                       ((unsigned)f32_to_bf16_rne(o1.w) << 16);
                *(uint2*)(OutBf + (size_t)gr * D + tx * 4) = p0;
                *(uint2*)(OutBf + (size_t)gr * D + 64 + tx * 4) = p1;
            }
        }
    }
}

// ---------------------------------------------------------------------------
// Launch
// ---------------------------------------------------------------------------
extern "C" void kernel_launch(void* const* d_in, const int* in_sizes, int n_in,
                              void* d_out, int out_size, void* d_ws,
                              size_t ws_size, hipStream_t stream) {
    const float* x   = (const float*)d_in[0];
    const int*   ei  = (const int*)d_in[1];   // [2, E]: row0 = src, row1 = dst
    // d_in[2] edge_weight: unused by the reference
    const float* W0l = (const float*)d_in[3];
    const float* b0l = (const float*)d_in[4];
    const float* W0r = (const float*)d_in[5];
    const float* W2l = (const float*)d_in[6];
    const float* b2l = (const float*)d_in[7];
    const float* W2r = (const float*)d_in[8];

    const int* src = ei;
    const int* dst = ei + N_EDGES;

    float* fea = (float*)d_out;            // output 0: [N,128] (final)
    float* h   = (float*)d_out + NF;       // output 1 (mid feats): [N,128]
    float* meanbuf = fea;                  // fea slot doubles as mean scratch

    // workspace layout
    char* ws = (char*)d_ws;
    int* deg    = (int*)ws;                    //   400,000 B
    int* rowptr = (int*)(ws + 400000);         //   400,004 B
    int* bsums  = (int*)(ws + 800032);         //       512 B
    int* cursor = (int*)(ws + 800544);         //   400,000 B
    int* col    = (int*)(ws + 1200544);        // 6,400,000 B -> end 7,600,544
    unsigned short* xb = (unsigned short*)(ws + 7600640);  // 25,600,000 B bf16
    const bool use_bf16 = (ws_size >= (size_t)33200640);

    const int nScanBlocks = (N_NODES + 1023) / 1024;   // 98
    const int nChunks = (N_EDGES + EPB - 1) / EPB;     // 391

    // ---- build CSR (rebuilt every call; ws is re-poisoned) ----
    hipMemsetAsync(deg, 0, N_NODES * sizeof(int), stream);
    deg_count_part_kernel<<<nChunks * NGROUPS, 256, 0, stream>>>(dst, deg,
                                                                 N_EDGES);
    scan1_kernel<<<nScanBlocks, 1024, 0, stream>>>(deg, rowptr, bsums, N_NODES);
    scan2_kernel<<<1, 128, 0, stream>>>(bsums, nScanBlocks);
    scan3_kernel<<<nScanBlocks, 1024, 0, stream>>>(rowptr, bsums, cursor,
                                                   N_NODES, N_EDGES);
    csr_fill_part_kernel<<<nChunks * NGROUPS, 256, 0, stream>>>(src, dst,
                                                                cursor, col,
                                                                N_EDGES);

    const int aggGrid = (N_NODES * 64 + 255) / 256;      // one wave per node
    const int gemmGrid = (N_NODES + BM - 1) / BM;        // 1563

    if (use_bf16) {
        // x -> bf16 (one-shot); h_bf16 is emitted by the layer-0 GEMM into
        // the same buffer (x_bf16 is dead by then; stream-ordered).
        convert_bf16_kernel<<<(NF / 8 + 255) / 256, 256, 0, stream>>>(
            x, (unsigned*)xb, NF / 8);

        // ---- layer 0 ----
        aggregate_mean_bf16_kernel<<<aggGrid, 256, 0, stream>>>(xb, rowptr,
                                                                col, meanbuf);
        sage_gemm_kernel<<<gemmGrid, 256, 0, stream>>>(meanbuf, x, W0l, W0r,
                                                       b0l, h, xb, N_NODES);

        // ---- layer 1 (in place on fea) ----
        aggregate_mean_bf16_kernel<<<aggGrid, 256, 0, stream>>>(xb, rowptr,
                                                                col, meanbuf);
        sage_gemm_kernel<<<gemmGrid, 256, 0, stream>>>(meanbuf, h, W2l, W2r,
                                                       b2l, fea, (unsigned short*)nullptr,
                                                       N_NODES);
    } else {
        // ---- f32 fallback ----
        aggregate_mean_kernel<<<aggGrid, 256, 0, stream>>>(x, rowptr, col,
                                                           meanbuf);
        sage_gemm_kernel<<<gemmGrid, 256, 0, stream>>>(meanbuf, x, W0l, W0r,
                                                       b0l, h, (unsigned short*)nullptr,
                                                       N_NODES);
        aggregate_mean_kernel<<<aggGrid, 256, 0, stream>>>(h, rowptr, col,
                                                           meanbuf);
        sage_gemm_kernel<<<gemmGrid, 256, 0, stream>>>(meanbuf, h, W2l, W2r,
                                                       b2l, fea, (unsigned short*)nullptr,
                                                       N_NODES);
    }
}